// Round 11
// baseline (6156.737 us; speedup 1.0000x reference)
//
#include <hip/hip_runtime.h>

#define Ssz 512
#define BT  64     // rows per rowtile
#define SLC 32     // h-cols per slice

typedef __attribute__((ext_vector_type(8))) short short8;
typedef __attribute__((ext_vector_type(4))) float f32x4;
typedef __attribute__((ext_vector_type(4))) unsigned uint4v;

// ---- ws layout (bytes) ----
#define WS_PW   0u            // 1.5 MB packed gate weights
#define WS_PW1  1572864u      // 256 KB packed W1
#define WS_HB   1835008u      // 2 MB Hbuf[2][1024][512] bf16
#define WS_PX   3932160u      // 128 KB px[rt16][row64][c2][sl16] f32
#define WS_BAR  4456448u      // 8 KB: fl1[16][64] + fl2[16][64]

__device__ __forceinline__ unsigned short f2bf(float f) {
  unsigned int u = __builtin_bit_cast(unsigned int, f);
  u += 0x7fffu + ((u >> 16) & 1u);   // RNE (finite inputs)
  return (unsigned short)(u >> 16);
}
__device__ __forceinline__ float sigm(float x) {
  x = fminf(fmaxf(x, -30.f), 30.f);
  return 1.f / (1.f + __expf(-x));
}
__device__ __forceinline__ float tanh_f(float x) {
  x = fminf(fmaxf(x, -15.f), 15.f);
  float e = __expf(2.f * x);
  return (e - 1.f) / (e + 1.f);
}

// ---- cache-bypassing (device-coherent) ops: data lives at MALL (proven
// R5/R9 transport; R10's sc0-only L2 ring deadlocked -> abandoned). ----
__device__ __forceinline__ uint4v gload16(const void* p) {
  uint4v d;
  asm volatile("global_load_dwordx4 %0, %1, off sc0 sc1" : "=v"(d) : "v"(p));
  return d;
}
__device__ __forceinline__ unsigned gload4(const void* p) {
  unsigned d;
  asm volatile("global_load_dword %0, %1, off sc0 sc1" : "=v"(d) : "v"(p));
  return d;
}
__device__ __forceinline__ void gstore16(void* p, uint4v v) {
  asm volatile("global_store_dwordx4 %0, %1, off sc0 sc1" :: "v"(p), "v"(v) : "memory");
}
__device__ __forceinline__ void gstore4(void* p, unsigned v) {
  asm volatile("global_store_dword %0, %1, off sc0 sc1" :: "v"(p), "v"(v) : "memory");
}
__device__ __forceinline__ void vwait0() {
  asm volatile("s_waitcnt vmcnt(0)" ::: "memory");
  __builtin_amdgcn_sched_barrier(0);
}

// All-lane poll of 32 per-wave flags (lane l polls base[idx(l&31)]).
__device__ __forceinline__ void pollflags(const unsigned* fp, unsigned target) {
  for (;;) {
    unsigned v = gload4(fp);
    vwait0();
    if (__all((int)(v >= target))) break;
    __builtin_amdgcn_s_sleep(1);
  }
}

// Pack W_hh [1536,512] f32 -> fragment-ordered bf16 (R5/R9 layout, unchanged).
// byte offset (((sl*6+q)*16+kk)*64+l)*16 ; q = gate*2+ch
// holds W_hh[gate*512 + sl*32 + ch*16 + (l&15)][kk*32 + (l>>4)*8 + e]
// Block 0 zeroes BOTH flag arrays (2048 words) every launch.
__global__ void pack_whh_k(const float* __restrict__ Wp, unsigned short* __restrict__ dst,
                           unsigned* __restrict__ barz) {
  if (blockIdx.x == 0) {
    for (int i = threadIdx.x; i < 2048; i += 256) barz[i] = 0u;
  }
  int T = blockIdx.x * 256 + threadIdx.x;
  int l  = T & 63;
  int r1 = T >> 6;
  int kk = r1 & 15;
  int r2 = r1 >> 4;
  int q  = r2 % 6;
  int sl = r2 / 6;
  int g = q >> 1, ch = q & 1;
  int j  = g * 512 + sl * 32 + ch * 16 + (l & 15);
  int kb = kk * 32 + (l >> 4) * 8;
  const float* src = Wp + j * 512 + kb;
  short8 o;
#pragma unroll
  for (int e = 0; e < 8; ++e) o[e] = (short)f2bf(src[e]);
  *reinterpret_cast<short8*>(dst + (size_t)T * 8) = o;
}

// Pack W1 [256,512] f32 -> fragment-ordered bf16 (unchanged).
__global__ void pack_w1_k(const float* __restrict__ W1, unsigned short* __restrict__ dst) {
  int T = blockIdx.x * 256 + threadIdx.x;
  int l  = T & 63;
  int r1 = T >> 6;
  int kk = r1 & 15;
  int sl = r1 >> 4;
  int j  = sl * 16 + (l & 15);
  int kb = kk * 32 + (l >> 4) * 8;
  const float* src = W1 + j * 512 + kb;
  short8 o;
#pragma unroll
  for (int e = 0; e < 8; ++e) o[e] = (short)f2bf(src[e]);
  *reinterpret_cast<short8*>(dst + (size_t)T * 8) = o;
}

// swizzled hfull byte address: row-major [64][512] bf16 with XOR on bits 4..6
__device__ __forceinline__ int haddr(int rowbase, int sw, int ld, int kk) {
  return rowbase + (((ld << 4) + (kk << 6)) ^ sw);
}

// 256 WGs x 256 threads, plain launch. R9 skeleton with wave-granular sync:
// - h flags fl1[rt][sl*4+w]: wave w publishes rows (w>>1)*32..+32 x cols
//   ch*16 of its slice right after ITS gate math (no pre-publish barrier).
// - px flags fl2[rt][sl*4+w]: wave w publishes px rows w*16..+16 right after
//   ITS MLP (no barrier).
// - consumers poll the 32 producer-wave flags they depend on (lanes 0..31).
// - x tracked redundantly per wave in registers (rows rfh*32..+32); x,v
//   distributed to gate lanes via __shfl; xg LDS + its barrier deleted.
// - ONE __syncthreads per step (orders all waves' FILL before gh GEMM).
__global__ __launch_bounds__(256, 1) void gru_main(
    const float* __restrict__ X0, const float* __restrict__ V,
    const float* __restrict__ Wih, const float* __restrict__ bih,
    const float* __restrict__ bhh, const float* __restrict__ b1,
    const float* __restrict__ W2, const float* __restrict__ b2,
    const unsigned short* __restrict__ PW, const unsigned short* __restrict__ PW1,
    unsigned short* __restrict__ Hb, float* __restrict__ px,
    unsigned* __restrict__ bar, float* __restrict__ out)
{
  __shared__ alignas(16) unsigned short hfull[BT * 512];    // 64 KB, swizzled
  __shared__ alignas(16) unsigned short hstage[4][32][16];  // 4 KB per-wave

  const int tid = threadIdx.x;
  const int l  = tid & 63, w = tid >> 6;
  const int lm = l & 15,  ld = l >> 4;
  const int rt = blockIdx.x & 15, sl = blockIdx.x >> 4;
  const int rfh = w >> 1, ch = w & 1;
  const int row0 = rt * BT;
  char* hfullB = reinterpret_cast<char*>(hfull);

  unsigned* fl1 = bar + rt * 64;          // [sl*4+w] : h rows (w>>1)*32, cols ch*16; value = step+1
  unsigned* fl2 = bar + 1024 + rt * 64;   // [sl*4+w] : px rows w*16..+16; value = step

  // poll index: 32 flags = all slices x the 2 producer waves of this row-half
  const int pj = l & 31;
  const int pidx = (pj >> 1) * 4 + (w & ~1) + (pj & 1);
  const unsigned* p1 = fl1 + pidx;
  const unsigned* p2 = fl2 + pidx;

  // ---- persistent weight fragments in registers (loaded once) ----
  short8 BW[3][16];
  {
    const char* pwb = reinterpret_cast<const char*>(PW);
#pragma unroll
    for (int g = 0; g < 3; ++g)
#pragma unroll
      for (int kk = 0; kk < 16; ++kk)
        BW[g][kk] = *reinterpret_cast<const short8*>(
            pwb + (size_t)((((sl * 6 + g * 2 + ch) * 16 + kk) * 64 + l) * 16));
  }
  short8 BM[16];
  {
    const char* pw1b = reinterpret_cast<const char*>(PW1);
#pragma unroll
    for (int kk = 0; kk < 16; ++kk)
      BM[kk] = *reinterpret_cast<const short8*>(
          pw1b + (size_t)(((sl * 16 + kk) * 64 + l) * 16));
  }

  // ---- per-lane constants (gate cols: jcol; MLP hidden: ic) ----
  const int jcol = sl * SLC + ch * 16 + lm;
  f32x4 wvx[3]; float bi[3], bh[3];
#pragma unroll
  for (int g = 0; g < 3; ++g) {
    int jg = g * 512 + jcol;
    wvx[g] = *reinterpret_cast<const f32x4*>(Wih + (size_t)jg * 4);
    bi[g] = bih[jg];
    bh[g] = bhh[jg];
  }
  const int ic = sl * 16 + lm;
  const float b1v = b1[ic];
  const float w2a = W2[ic], w2b = W2[256 + ic];
  const float b2c = b2[l & 1];

  // ---- per-wave redundant x-state: lane l <-> (row = rfh*32 + (l>>1), c = l&1) ----
  const int xrow = rfh * 32 + (l >> 1);
  const int xc   = l & 1;
  float xcur = X0[(row0 + xrow) * 2 + xc];                      // x_{-1}
  float vcur = V[(size_t)(row0 + xrow) * (Ssz * 2) + xc];       // v_0

  float hp[2][4];
#pragma unroll
  for (int q = 0; q < 2; ++q)
#pragma unroll
    for (int r = 0; r < 4; ++r) hp[q][r] = 0.f;

  const int rbA0 = (rfh * 32 + lm) * 1024,      swA0 = ((rfh * 32 + lm) & 7) << 4;
  const int rbA1 = (rfh * 32 + 16 + lm) * 1024, swA1 = ((rfh * 32 + 16 + lm) & 7) << 4;
  const int rbB  = (w * 16 + lm) * 1024,        swB  = ((w * 16 + lm) & 7) << 4;

  for (int i = 0; i <= Ssz; ++i) {
    f32x4 acc[2][3];
#pragma unroll
    for (int q = 0; q < 2; ++q)
#pragma unroll
      for (int g = 0; g < 3; ++g) acc[q][g] = (f32x4){0.f, 0.f, 0.f, 0.f};

    if (i > 0) {
      // ---- poll S1(i): the 32 producer waves of this row-half published h_{i-1} ----
      pollflags(p1, (unsigned)i);

      // ---- FILL: wave w stages rows w*16..+16 of h_{i-1} -> swizzled LDS ----
      {
        const char* hsrc = reinterpret_cast<const char*>(
            Hb + (size_t)((i - 1) & 1) * (1024 * 512) + (size_t)row0 * 512);
        uint4v fb[16];
#pragma unroll
        for (int j = 0; j < 16; ++j)
          fb[j] = gload16(hsrc + (size_t)(w * 16 + j) * 1024 + l * 16);
        vwait0();
#pragma unroll
        for (int j = 0; j < 16; ++j) {
          const int m = w * 16 + j;
          *reinterpret_cast<uint4v*>(hfullB + m * 1024 + ((l * 16) ^ ((m & 7) << 4))) = fb[j];
        }
      }

      // ---- MLP on rows w*16..+16 of h_{i-1}: px partial -> publish -> fl2 ----
      {
        f32x4 am = (f32x4){0.f, 0.f, 0.f, 0.f};
#pragma unroll
        for (int kk = 0; kk < 16; ++kk) {
          short8 a = *reinterpret_cast<const short8*>(hfullB + haddr(rbB, swB, ld, kk));
          am = __builtin_amdgcn_mfma_f32_16x16x32_bf16(a, BM[kk], am, 0, 0, 0);
        }
        float pa[4], pb[4];
#pragma unroll
        for (int r = 0; r < 4; ++r) {
          float mv = fmaxf(am[r] + b1v, 0.f);
          pa[r] = mv * w2a;
          pb[r] = mv * w2b;
        }
#pragma unroll
        for (int off = 1; off < 16; off <<= 1)
#pragma unroll
          for (int r = 0; r < 4; ++r) {
            pa[r] += __shfl_xor(pa[r], off);
            pb[r] += __shfl_xor(pb[r], off);
          }
        if (lm == 0) {
#pragma unroll
          for (int r = 0; r < 4; ++r) {
            int row = w * 16 + ld * 4 + r;
            float* p0 = px + ((size_t)(rt * 64 + row) * 2 + 0) * 16 + sl;
            float* p1s = px + ((size_t)(rt * 64 + row) * 2 + 1) * 16 + sl;
            gstore4(p0, __builtin_bit_cast(unsigned, pa[r]));
            gstore4(p1s, __builtin_bit_cast(unsigned, pb[r]));
          }
        }
        asm volatile("s_waitcnt vmcnt(0)" ::: "memory");   // own px at MALL
        if (l == 0) gstore4(fl2 + sl * 4 + w, (unsigned)i);
      }
      __syncthreads();   // THE one barrier: all waves' FILL visible for gh GEMM

      // ---- gh GEMM for step i ----
      if (i < Ssz) {
#pragma unroll
        for (int kk = 0; kk < 16; ++kk) {
          short8 a0 = *reinterpret_cast<const short8*>(hfullB + haddr(rbA0, swA0, ld, kk));
          short8 a1 = *reinterpret_cast<const short8*>(hfullB + haddr(rbA1, swA1, ld, kk));
          acc[0][0] = __builtin_amdgcn_mfma_f32_16x16x32_bf16(a0, BW[0][kk], acc[0][0], 0, 0, 0);
          acc[1][0] = __builtin_amdgcn_mfma_f32_16x16x32_bf16(a1, BW[0][kk], acc[1][0], 0, 0, 0);
          acc[0][1] = __builtin_amdgcn_mfma_f32_16x16x32_bf16(a0, BW[1][kk], acc[0][1], 0, 0, 0);
          acc[1][1] = __builtin_amdgcn_mfma_f32_16x16x32_bf16(a1, BW[1][kk], acc[1][1], 0, 0, 0);
          acc[0][2] = __builtin_amdgcn_mfma_f32_16x16x32_bf16(a0, BW[2][kk], acc[0][2], 0, 0, 0);
          acc[1][2] = __builtin_amdgcn_mfma_f32_16x16x32_bf16(a1, BW[2][kk], acc[1][2], 0, 0, 0);
        }
      }

      // ---- poll S2(i): px(i-1) of this row-half from all slices ----
      pollflags(p2, (unsigned)i);

      // ---- x update (per wave, all lanes): x_{i-1} = x_{i-2} + v_{i-1} + res ----
      {
        const float* pc = px + ((size_t)(rt * 64 + xrow) * 2 + xc) * 16;
        f32x4 s0 = __builtin_bit_cast(f32x4, gload16(pc + 0));
        f32x4 s1 = __builtin_bit_cast(f32x4, gload16(pc + 4));
        f32x4 s2 = __builtin_bit_cast(f32x4, gload16(pc + 8));
        f32x4 s3 = __builtin_bit_cast(f32x4, gload16(pc + 12));
        vwait0();
        float s = b2c;
#pragma unroll
        for (int r = 0; r < 4; ++r) s += s0[r] + s1[r] + s2[r] + s3[r];
        float xt = xcur + vcur + s;
        xcur = xt;
        if (sl == 0 && ch == 0)
          out[(size_t)(row0 + xrow) * (Ssz * 2) + (i - 1) * 2 + xc] = xt;
        vcur = (i < Ssz) ? V[(size_t)(row0 + xrow) * (Ssz * 2) + i * 2 + xc] : 0.f;
      }
    }

    if (i < Ssz) {
      // ---- gate math -> h_i (x,v via intra-wave shuffles; no barrier) ----
#pragma unroll
      for (int rf2 = 0; rf2 < 2; ++rf2) {
#pragma unroll
        for (int r = 0; r < 4; ++r) {
          const int rl = rf2 * 16 + ld * 4 + r;       // row-local in rfh half
          float v0 = __shfl(vcur, rl * 2);
          float v1 = __shfl(vcur, rl * 2 + 1);
          float x0 = __shfl(xcur, rl * 2);
          float x1 = __shfl(xcur, rl * 2 + 1);
          float gv0 = wvx[0][0]*v0 + wvx[0][1]*v1 + wvx[0][2]*x0 + wvx[0][3]*x1;
          float gv1 = wvx[1][0]*v0 + wvx[1][1]*v1 + wvx[1][2]*x0 + wvx[1][3]*x1;
          float gv2 = wvx[2][0]*v0 + wvx[2][1]*v1 + wvx[2][2]*x0 + wvx[2][3]*x1;
          float rr = sigm(gv0 + bi[0] + bh[0] + acc[rf2][0][r]);
          float zz = sigm(gv1 + bi[1] + bh[1] + acc[rf2][1][r]);
          float nn = tanh_f(gv2 + bi[2] + rr * (acc[rf2][2][r] + bh[2]));
          float ht = (1.f - zz) * nn + zz * hp[rf2][r];
          hp[rf2][r] = ht;
          hstage[w][rl][lm] = f2bf(ht);
        }
      }
      // ---- per-wave publish h_i rows rfh*32..+32 x cols ch*16 + fl1 = i+1 ----
      {
        asm volatile("s_waitcnt lgkmcnt(0)" ::: "memory");  // hstage writes done (wave-local)
        __builtin_amdgcn_sched_barrier(0);
        const int prow = l >> 1, seg = l & 1;
        uint4v hv = *reinterpret_cast<const uint4v*>(&hstage[w][prow][seg * 8]);
        gstore16(Hb + (size_t)(i & 1) * (1024 * 512)
                    + (size_t)(row0 + rfh * 32 + prow) * 512 + sl * 32 + ch * 16 + seg * 8, hv);
        asm volatile("s_waitcnt vmcnt(0)" ::: "memory");
        if (l == 0) gstore4(fl1 + sl * 4 + w, (unsigned)(i + 1));
      }
    }
  }
}

extern "C" void kernel_launch(void* const* d_in, const int* in_sizes, int n_in,
                              void* d_out, int out_size, void* d_ws, size_t ws_size,
                              hipStream_t stream) {
  const float* X0  = (const float*)d_in[0];
  const float* V   = (const float*)d_in[1];
  const float* Wih = (const float*)d_in[2];
  const float* Whh = (const float*)d_in[3];
  const float* bih = (const float*)d_in[4];
  const float* bhh = (const float*)d_in[5];
  const float* W1  = (const float*)d_in[6];
  const float* b1  = (const float*)d_in[7];
  const float* W2  = (const float*)d_in[8];
  const float* b2  = (const float*)d_in[9];
  float* out = (float*)d_out;

  char* ws = (char*)d_ws;
  unsigned short* PW  = (unsigned short*)(ws + WS_PW);
  unsigned short* PW1 = (unsigned short*)(ws + WS_PW1);
  unsigned short* Hb  = (unsigned short*)(ws + WS_HB);
  float*          px  = (float*)(ws + WS_PX);
  unsigned*       bar = (unsigned*)(ws + WS_BAR);

  pack_whh_k<<<384, 256, 0, stream>>>(Whh, PW, bar);
  pack_w1_k<<<64, 256, 0, stream>>>(W1, PW1);
  gru_main<<<256, 256, 0, stream>>>(X0, V, Wih, bih, bhh, b1, W2, b2,
                                    PW, PW1, Hb, px, bar, out);
}

// Round 12
// 6041.591 us; speedup vs baseline: 1.0191x; 1.0191x over previous
//
#include <hip/hip_runtime.h>

#define Ssz 512

typedef __attribute__((ext_vector_type(8))) short short8;
typedef __attribute__((ext_vector_type(4))) float f32x4;
typedef __attribute__((ext_vector_type(4))) unsigned uint4v;

// ---- ws layout (bytes) ----
#define WS_PW   0u            // 1.5 MB packed gate weights
#define WS_PW1  1572864u      // 256 KB packed W1
#define WS_HB   1835008u      // 2 MB Hbuf[2][1024][512] bf16
#define WS_PX   3932160u      // 128 KB px[rt32][row32][c2][sl16] f32
#define WS_BAR  4456448u      // 16 KB: fl1[rt32][sl16][rfh2][ch2] + fl2[rt32][sl16][mw2]

__device__ __forceinline__ unsigned short f2bf(float f) {
  unsigned int u = __builtin_bit_cast(unsigned int, f);
  u += 0x7fffu + ((u >> 16) & 1u);   // RNE (finite inputs)
  return (unsigned short)(u >> 16);
}
__device__ __forceinline__ float sigm(float x) {
  x = fminf(fmaxf(x, -30.f), 30.f);
  return 1.f / (1.f + __expf(-x));
}
__device__ __forceinline__ float tanh_f(float x) {
  x = fminf(fmaxf(x, -15.f), 15.f);
  float e = __expf(2.f * x);
  return (e - 1.f) / (e + 1.f);
}

// ---- cache-bypassing (device-coherent) ops: data lives at MALL (verified
// R5/R9 transport). ----
__device__ __forceinline__ uint4v gload16(const void* p) {
  uint4v d;
  asm volatile("global_load_dwordx4 %0, %1, off sc0 sc1" : "=v"(d) : "v"(p));
  return d;
}
__device__ __forceinline__ unsigned gload4(const void* p) {
  unsigned d;
  asm volatile("global_load_dword %0, %1, off sc0 sc1" : "=v"(d) : "v"(p));
  return d;
}
__device__ __forceinline__ void gstore16(void* p, uint4v v) {
  asm volatile("global_store_dwordx4 %0, %1, off sc0 sc1" :: "v"(p), "v"(v) : "memory");
}
__device__ __forceinline__ void gstore4(void* p, unsigned v) {
  asm volatile("global_store_dword %0, %1, off sc0 sc1" :: "v"(p), "v"(v) : "memory");
}
__device__ __forceinline__ void vwait0() {
  asm volatile("s_waitcnt vmcnt(0)" ::: "memory");
  __builtin_amdgcn_sched_barrier(0);
}
// All-lane poll: lane polls one flag, wave proceeds on __all (R9-verified).
__device__ __forceinline__ void pollflags(const unsigned* fp, unsigned target) {
  for (;;) {
    unsigned v = gload4(fp);
    vwait0();
    if (__all((int)(v >= target))) break;
    __builtin_amdgcn_s_sleep(1);
  }
}

// Pack W_hh [1536,512] f32 -> fragment-ordered bf16 (R9 layout, unchanged:
// column mapping only, row-count independent).
// byte offset (((sl*6+q)*16+kk)*64+l)*16 ; q = gate*2+ch
// holds W_hh[gate*512 + sl*32 + ch*16 + (l&15)][kk*32 + (l>>4)*8 + e]
// Block 0 zeroes all 4096 flag words every launch (replay determinism).
__global__ void pack_whh_k(const float* __restrict__ Wp, unsigned short* __restrict__ dst,
                           unsigned* __restrict__ barz) {
  if (blockIdx.x == 0) {
    for (int i = threadIdx.x; i < 4096; i += 256) barz[i] = 0u;
  }
  int T = blockIdx.x * 256 + threadIdx.x;
  int l  = T & 63;
  int r1 = T >> 6;
  int kk = r1 & 15;
  int r2 = r1 >> 4;
  int q  = r2 % 6;
  int sl = r2 / 6;
  int g = q >> 1, ch = q & 1;
  int j  = g * 512 + sl * 32 + ch * 16 + (l & 15);
  int kb = kk * 32 + (l >> 4) * 8;
  const float* src = Wp + j * 512 + kb;
  short8 o;
#pragma unroll
  for (int e = 0; e < 8; ++e) o[e] = (short)f2bf(src[e]);
  *reinterpret_cast<short8*>(dst + (size_t)T * 8) = o;
}

// Pack W1 [256,512] f32 -> fragment-ordered bf16 (unchanged).
__global__ void pack_w1_k(const float* __restrict__ W1, unsigned short* __restrict__ dst) {
  int T = blockIdx.x * 256 + threadIdx.x;
  int l  = T & 63;
  int r1 = T >> 6;
  int kk = r1 & 15;
  int sl = r1 >> 4;
  int j  = sl * 16 + (l & 15);
  int kb = kk * 32 + (l >> 4) * 8;
  const float* src = W1 + j * 512 + kb;
  short8 o;
#pragma unroll
  for (int e = 0; e < 8; ++e) o[e] = (short)f2bf(src[e]);
  *reinterpret_cast<short8*>(dst + (size_t)T * 8) = o;
}

// 256 WGs x 256 threads. Each WG runs TWO independent rings (32-row rowtiles
// rtA = 2*rp, rtB = 2*rp+1; same col slice -> shared weight regs). Per iter:
// waves 0,1 run ring A's poll/FILL/MLP/px (rows (w&1)*16..+16, wave-local);
// waves 2,3 run ring B's -> B1 barrier -> all waves GEMM both rings (wave =
// (rfh,ch) role, a0/a1 = ring A/B row) -> waves 0,2 poll px + x-update per
// ring -> B2 barrier -> gates+publish both rings (wave-local flags).
// Ring A's MALL RTs overlap ring B's compute and vice versa. LDS padded to
// ~84 KB -> exactly 1 WG/CU (prevents 2-WG compaction idling CUs).
__global__ __launch_bounds__(256, 1) void gru_main(
    const float* __restrict__ X0, const float* __restrict__ V,
    const float* __restrict__ Wih, const float* __restrict__ bih,
    const float* __restrict__ bhh, const float* __restrict__ b1,
    const float* __restrict__ W2, const float* __restrict__ b2,
    const unsigned short* __restrict__ PW, const unsigned short* __restrict__ PW1,
    unsigned short* __restrict__ Hb, float* __restrict__ px,
    unsigned* __restrict__ bar, float* __restrict__ out)
{
  __shared__ alignas(16) unsigned short hfA[32 * 512];      // 32 KB, swizzled
  __shared__ alignas(16) unsigned short hfB[32 * 512];      // 32 KB, swizzled
  __shared__ alignas(16) unsigned short hstage[2][32][40];  // 5 KB
  __shared__ alignas(16) float xg[2][32][4];                // 1 KB [v0,v1,x0,x1]
  __shared__ char lds_pad[12288];                           // force 1 WG/CU

  const int tid = threadIdx.x;
  const int l  = tid & 63, w = tid >> 6;
  const int lm = l & 15,  ld = l >> 4;
  const int rp = blockIdx.x & 15, sl = blockIdx.x >> 4;
  const int rtA = rp * 2;
  if (out == nullptr) lds_pad[tid] = 1;   // keep pad live (never executes)

  const int tw = w >> 1, mw = w & 1;      // team role: ring, 16-row tile
  const int rfh = w >> 1, ch = w & 1;     // gemm/gates role: row-half, col-half
  char* hfAB = reinterpret_cast<char*>(hfA);
  char* hfBB = reinterpret_cast<char*>(hfB);
  unsigned* fl2b = bar + 2048;

  // ---- persistent weight fragments (loaded once; shared by both rings) ----
  short8 BW[3][16];
  {
    const char* pwb = reinterpret_cast<const char*>(PW);
#pragma unroll
    for (int g = 0; g < 3; ++g)
#pragma unroll
      for (int kk = 0; kk < 16; ++kk)
        BW[g][kk] = *reinterpret_cast<const short8*>(
            pwb + (size_t)((((sl * 6 + g * 2 + ch) * 16 + kk) * 64 + l) * 16));
  }
  short8 BM[16];
  {
    const char* pw1b = reinterpret_cast<const char*>(PW1);
#pragma unroll
    for (int kk = 0; kk < 16; ++kk)
      BM[kk] = *reinterpret_cast<const short8*>(
          pw1b + (size_t)(((sl * 16 + kk) * 64 + l) * 16));
  }

  // ---- per-lane constants ----
  const int jcol = sl * 32 + ch * 16 + lm;
  f32x4 wvx[3]; float bi[3], bh[3];
#pragma unroll
  for (int g = 0; g < 3; ++g) {
    int jg = g * 512 + jcol;
    wvx[g] = *reinterpret_cast<const f32x4*>(Wih + (size_t)jg * 4);
    bi[g] = bih[jg];
    bh[g] = bhh[jg];
  }
  const int ic = sl * 16 + lm;
  const float b1v = b1[ic];
  const float w2a = W2[ic], w2b = W2[256 + ic];
  const float b2c = b2[l & 1];

  // ---- x state (waves 0,2 own ring w>>1; lane l <-> row l>>1, col l&1) ----
  float xcur = 0.f, vcur = 0.f;
  if ((w & 1) == 0) {
    const int ring = w >> 1;
    const int row0t = (rtA + ring) * 32;
    const int row = l >> 1, c = l & 1;
    xcur = X0[(row0t + row) * 2 + c];
    vcur = V[(size_t)(row0t + row) * 1024 + c];   // v_0
    xg[ring][row][c] = vcur;
    xg[ring][row][2 + c] = xcur;
  }
  float hp[2][4];
#pragma unroll
  for (int q = 0; q < 2; ++q)
#pragma unroll
    for (int r = 0; r < 4; ++r) hp[q][r] = 0.f;
  __syncthreads();

  for (int i = 0; i <= Ssz; ++i) {
    f32x4 acc[2][3];
#pragma unroll
    for (int q = 0; q < 2; ++q)
#pragma unroll
      for (int g = 0; g < 3; ++g) acc[q][g] = (f32x4){0.f, 0.f, 0.f, 0.f};

    if (i > 0) {
      // ======== team phase: wave (tw,mw) services its ring's 16 rows ========
      {
        const int rt_t = rtA + tw;
        const int row0t = rt_t * 32;
        char* hfT = tw ? hfBB : hfAB;
        // poll S1(i): producer waves (rfh=mw, ch=0/1) of all 16 slices
        pollflags(bar + (((rt_t * 16 + (l & 15)) * 2 + mw) * 2 + ((l >> 4) & 1)),
                  (unsigned)i);
        // FILL rows mw*16..+16 of h_{i-1} -> swizzled LDS
        const char* hsrc = reinterpret_cast<const char*>(
            Hb + (size_t)((i - 1) & 1) * (1024 * 512)) + (size_t)row0t * 1024;
        uint4v fb[16];
#pragma unroll
        for (int j = 0; j < 16; ++j)
          fb[j] = gload16(hsrc + (size_t)(mw * 16 + j) * 1024 + l * 16);
        vwait0();
#pragma unroll
        for (int j = 0; j < 16; ++j) {
          const int m = mw * 16 + j;
          *reinterpret_cast<uint4v*>(hfT + m * 1024 + ((l * 16) ^ ((m & 7) << 4))) = fb[j];
        }
        // MLP on rows mw*16..+16 -> px -> flag2
        const int rbB = (mw * 16 + lm) * 1024, swB = (lm & 7) << 4;
        f32x4 am = (f32x4){0.f, 0.f, 0.f, 0.f};
#pragma unroll
        for (int kk = 0; kk < 16; ++kk) {
          short8 a = *reinterpret_cast<const short8*>(hfT + rbB + ((ld * 16 + kk * 64) ^ swB));
          am = __builtin_amdgcn_mfma_f32_16x16x32_bf16(a, BM[kk], am, 0, 0, 0);
        }
        float pa[4], pb[4];
#pragma unroll
        for (int r = 0; r < 4; ++r) {
          float mv = fmaxf(am[r] + b1v, 0.f);
          pa[r] = mv * w2a;
          pb[r] = mv * w2b;
        }
#pragma unroll
        for (int off = 1; off < 16; off <<= 1)
#pragma unroll
          for (int r = 0; r < 4; ++r) {
            pa[r] += __shfl_xor(pa[r], off);
            pb[r] += __shfl_xor(pb[r], off);
          }
        if (lm == 0) {
#pragma unroll
          for (int r = 0; r < 4; ++r) {
            int row = mw * 16 + ld * 4 + r;
            gstore4(px + ((size_t)(rt_t * 32 + row) * 2 + 0) * 16 + sl,
                    __builtin_bit_cast(unsigned, pa[r]));
            gstore4(px + ((size_t)(rt_t * 32 + row) * 2 + 1) * 16 + sl,
                    __builtin_bit_cast(unsigned, pb[r]));
          }
        }
        asm volatile("s_waitcnt vmcnt(0)" ::: "memory");   // own px at MALL
        if (l == 0) gstore4(fl2b + (rt_t * 16 + sl) * 2 + mw, (unsigned)i);
      }
      __syncthreads();   // B1: both hfulls complete

      // ======== gh GEMM both rings (a0 = ring A row, a1 = ring B row) ========
      if (i < Ssz) {
        const int rbA = (rfh * 16 + lm) * 1024, swA = (lm & 7) << 4;
#pragma unroll
        for (int kk = 0; kk < 16; ++kk) {
          const int o = (ld * 16 + kk * 64) ^ swA;
          short8 a0 = *reinterpret_cast<const short8*>(hfAB + rbA + o);
          short8 a1 = *reinterpret_cast<const short8*>(hfBB + rbA + o);
          acc[0][0] = __builtin_amdgcn_mfma_f32_16x16x32_bf16(a0, BW[0][kk], acc[0][0], 0, 0, 0);
          acc[1][0] = __builtin_amdgcn_mfma_f32_16x16x32_bf16(a1, BW[0][kk], acc[1][0], 0, 0, 0);
          acc[0][1] = __builtin_amdgcn_mfma_f32_16x16x32_bf16(a0, BW[1][kk], acc[0][1], 0, 0, 0);
          acc[1][1] = __builtin_amdgcn_mfma_f32_16x16x32_bf16(a1, BW[1][kk], acc[1][1], 0, 0, 0);
          acc[0][2] = __builtin_amdgcn_mfma_f32_16x16x32_bf16(a0, BW[2][kk], acc[0][2], 0, 0, 0);
          acc[1][2] = __builtin_amdgcn_mfma_f32_16x16x32_bf16(a1, BW[2][kk], acc[1][2], 0, 0, 0);
        }
      }

      // ======== x phase: wave 0 -> ring A, wave 2 -> ring B ========
      if ((w & 1) == 0) {
        const int ring = w >> 1;
        const int rt_t = rtA + ring, row0t = rt_t * 32;
        pollflags(fl2b + (rt_t * 16 + (l & 15)) * 2 + (l >> 5), (unsigned)i);
        const int row = l >> 1, c = l & 1;
        const float* pc = px + ((size_t)(rt_t * 32 + row) * 2 + c) * 16;
        f32x4 s0 = __builtin_bit_cast(f32x4, gload16(pc + 0));
        f32x4 s1 = __builtin_bit_cast(f32x4, gload16(pc + 4));
        f32x4 s2 = __builtin_bit_cast(f32x4, gload16(pc + 8));
        f32x4 s3 = __builtin_bit_cast(f32x4, gload16(pc + 12));
        vwait0();
        float s = b2c;
#pragma unroll
        for (int r = 0; r < 4; ++r) s += s0[r] + s1[r] + s2[r] + s3[r];
        float xt = xcur + vcur + s;
        xcur = xt;
        if (sl == 0) out[(size_t)(row0t + row) * 1024 + (i - 1) * 2 + c] = xt;
        vcur = (i < Ssz) ? V[(size_t)(row0t + row) * 1024 + i * 2 + c] : 0.f;
        xg[ring][row][c] = vcur;
        xg[ring][row][2 + c] = xt;
      }
      __syncthreads();   // B2: xg ready; all GEMM reads of hfull done
    }

    if (i < Ssz) {
      // ======== gates + wave-local publish, both rings ========
#pragma unroll
      for (int ring = 0; ring < 2; ++ring) {
        const int rt_t = rtA + ring, row0t = rt_t * 32;
#pragma unroll
        for (int r4 = 0; r4 < 4; ++r4) {
          const int m = rfh * 16 + ld * 4 + r4;
          const f32x4 xv = *reinterpret_cast<const f32x4*>(&xg[ring][m][0]);
          float gv0 = wvx[0][0]*xv[0] + wvx[0][1]*xv[1] + wvx[0][2]*xv[2] + wvx[0][3]*xv[3];
          float gv1 = wvx[1][0]*xv[0] + wvx[1][1]*xv[1] + wvx[1][2]*xv[2] + wvx[1][3]*xv[3];
          float gv2 = wvx[2][0]*xv[0] + wvx[2][1]*xv[1] + wvx[2][2]*xv[2] + wvx[2][3]*xv[3];
          float rr = sigm(gv0 + bi[0] + bh[0] + acc[ring][0][r4]);
          float zz = sigm(gv1 + bi[1] + bh[1] + acc[ring][1][r4]);
          float nn = tanh_f(gv2 + bi[2] + rr * (acc[ring][2][r4] + bh[2]));
          float ht = (1.f - zz) * nn + zz * hp[ring][r4];
          hp[ring][r4] = ht;
          hstage[ring][m][ch * 16 + lm] = f2bf(ht);
        }
        asm volatile("s_waitcnt lgkmcnt(0)" ::: "memory");  // own wave's hstage visible
        __builtin_amdgcn_sched_barrier(0);
        if (l < 32) {
          const int prow = rfh * 16 + (l >> 1), pck = l & 1;
          uint4v hv = *reinterpret_cast<const uint4v*>(&hstage[ring][prow][ch * 16 + pck * 8]);
          gstore16(Hb + (size_t)(i & 1) * (1024 * 512)
                      + (size_t)(row0t + prow) * 512 + sl * 32 + ch * 16 + pck * 8, hv);
        }
        asm volatile("s_waitcnt vmcnt(0)" ::: "memory");
        if (l == 0)
          gstore4(bar + (((rt_t * 16 + sl) * 2 + rfh) * 2 + ch), (unsigned)(i + 1));
      }
    }
  }
}

extern "C" void kernel_launch(void* const* d_in, const int* in_sizes, int n_in,
                              void* d_out, int out_size, void* d_ws, size_t ws_size,
                              hipStream_t stream) {
  const float* X0  = (const float*)d_in[0];
  const float* V   = (const float*)d_in[1];
  const float* Wih = (const float*)d_in[2];
  const float* Whh = (const float*)d_in[3];
  const float* bih = (const float*)d_in[4];
  const float* bhh = (const float*)d_in[5];
  const float* W1  = (const float*)d_in[6];
  const float* b1  = (const float*)d_in[7];
  const float* W2  = (const float*)d_in[8];
  const float* b2  = (const float*)d_in[9];
  float* out = (float*)d_out;

  char* ws = (char*)d_ws;
  unsigned short* PW  = (unsigned short*)(ws + WS_PW);
  unsigned short* PW1 = (unsigned short*)(ws + WS_PW1);
  unsigned short* Hb  = (unsigned short*)(ws + WS_HB);
  float*          px  = (float*)(ws + WS_PX);
  unsigned*       bar = (unsigned*)(ws + WS_BAR);

  pack_whh_k<<<384, 256, 0, stream>>>(Whh, PW, bar);
  pack_w1_k<<<64, 256, 0, stream>>>(W1, PW1);
  gru_main<<<256, 256, 0, stream>>>(X0, V, Wih, bih, bhh, b1, W2, b2,
                                    PW, PW1, Hb, px, bar, out);
}

// Round 13
// 4635.210 us; speedup vs baseline: 1.3283x; 1.3034x over previous
//
#include <hip/hip_runtime.h>

#define Ssz 512

typedef __attribute__((ext_vector_type(8))) short short8;
typedef __attribute__((ext_vector_type(4))) float f32x4;
typedef __attribute__((ext_vector_type(4))) unsigned uint4v;

// ---- ws layout (bytes) ----
#define WS_PW   0u            // 1.5 MB packed gate weights
#define WS_PW1  1572864u      // 256 KB packed W1
#define WS_HB   1835008u      // 2 MB Hbuf[2][1024][512] bf16
#define WS_PX   3932160u      // 128 KB px[rt64][row16][c2][slot16] f32
#define WS_BAR  4456448u      // 8 KB: fl1[rt64][sl4] + (at +1024 words) fl2[rt64][sl4]

__device__ __forceinline__ unsigned short f2bf(float f) {
  unsigned int u = __builtin_bit_cast(unsigned int, f);
  u += 0x7fffu + ((u >> 16) & 1u);   // RNE (finite inputs)
  return (unsigned short)(u >> 16);
}
__device__ __forceinline__ float sigm(float x) {
  x = fminf(fmaxf(x, -30.f), 30.f);
  return 1.f / (1.f + __expf(-x));
}
__device__ __forceinline__ float tanh_f(float x) {
  x = fminf(fmaxf(x, -15.f), 15.f);
  float e = __expf(2.f * x);
  return (e - 1.f) / (e + 1.f);
}

// ---- cache-bypassing (device-coherent) ops: data lives at MALL (verified
// R5/R9 transport). ----
__device__ __forceinline__ uint4v gload16(const void* p) {
  uint4v d;
  asm volatile("global_load_dwordx4 %0, %1, off sc0 sc1" : "=v"(d) : "v"(p));
  return d;
}
__device__ __forceinline__ unsigned gload4(const void* p) {
  unsigned d;
  asm volatile("global_load_dword %0, %1, off sc0 sc1" : "=v"(d) : "v"(p));
  return d;
}
__device__ __forceinline__ void gstore16(void* p, uint4v v) {
  asm volatile("global_store_dwordx4 %0, %1, off sc0 sc1" :: "v"(p), "v"(v) : "memory");
}
__device__ __forceinline__ void gstore4(void* p, unsigned v) {
  asm volatile("global_store_dword %0, %1, off sc0 sc1" :: "v"(p), "v"(v) : "memory");
}
__device__ __forceinline__ void vwait0() {
  asm volatile("s_waitcnt vmcnt(0)" ::: "memory");
  __builtin_amdgcn_sched_barrier(0);
}
// All-lane poll (R9-verified): lane polls one flag, wave proceeds on __all.
__device__ __forceinline__ void pollflags(const unsigned* fp, unsigned target) {
  for (;;) {
    unsigned v = gload4(fp);
    vwait0();
    if (__all((int)(v >= target))) break;
    __builtin_amdgcn_s_sleep(1);
  }
}

// Pack W_hh [1536,512] f32 -> fragment-ordered bf16 (layout unchanged from R9;
// it is a pure column-block mapping so the new 128-col slicing reuses it).
// byte offset (((cb>>1)*6+g*2+(cb&1))*16+kk)*64*16 + l*16 holds
// W_hh[g*512 + cb*16 + (l&15)][kk*32 + (l>>4)*8 + e], cb = 16-col block 0..31.
// Block 0 zeroes all 2048 flag words every launch.
__global__ void pack_whh_k(const float* __restrict__ Wp, unsigned short* __restrict__ dst,
                           unsigned* __restrict__ barz) {
  if (blockIdx.x == 0) {
    for (int i = threadIdx.x; i < 2048; i += 256) barz[i] = 0u;
  }
  int T = blockIdx.x * 256 + threadIdx.x;
  int l  = T & 63;
  int r1 = T >> 6;
  int kk = r1 & 15;
  int r2 = r1 >> 4;
  int q  = r2 % 6;
  int slO = r2 / 6;
  int g = q >> 1, ch = q & 1;
  int j  = g * 512 + slO * 32 + ch * 16 + (l & 15);
  int kb = kk * 32 + (l >> 4) * 8;
  const float* src = Wp + j * 512 + kb;
  short8 o;
#pragma unroll
  for (int e = 0; e < 8; ++e) o[e] = (short)f2bf(src[e]);
  *reinterpret_cast<short8*>(dst + (size_t)T * 8) = o;
}

// Pack W1 [256,512] f32 -> fragment-ordered bf16 (unchanged).
// [hb16][kk16][l64]x16B: holds W1[hb*16+(l&15)][kk*32+(l>>4)*8+e]
__global__ void pack_w1_k(const float* __restrict__ W1, unsigned short* __restrict__ dst) {
  int T = blockIdx.x * 256 + threadIdx.x;
  int l  = T & 63;
  int r1 = T >> 6;
  int kk = r1 & 15;
  int hb = r1 >> 4;
  int j  = hb * 16 + (l & 15);
  int kb = kk * 32 + (l >> 4) * 8;
  const float* src = W1 + j * 512 + kb;
  short8 o;
#pragma unroll
  for (int e = 0; e < 8; ++e) o[e] = (short)f2bf(src[e]);
  *reinterpret_cast<short8*>(dst + (size_t)T * 8) = o;
}

// 256 WGs x 256 threads: 64 rowtiles (16 rows) x 4 slices (128 gate cols).
// R9 protocol (WG flags, sc0sc1 MALL transport, same parity/ordering) with:
// - 4x less FILL traffic (16KB/WG/step) and 4x smaller poll fan-in (4);
// - gate weights 96 frags/wave in VGPRs (384); MLP W1 slice in LDS (64KB);
// - px slots [row][c][slot16] slot=sl*4+w -> x update reads 4x gload16;
// - out writes distributed: slice sl writes rows sl*4..+4 (no sl0 straggler).
// LDS ~84.5KB -> 1 WG/CU.
__global__ __launch_bounds__(256, 1) void gru_main(
    const float* __restrict__ X0, const float* __restrict__ V,
    const float* __restrict__ Wih, const float* __restrict__ bih,
    const float* __restrict__ bhh, const float* __restrict__ b1,
    const float* __restrict__ W2, const float* __restrict__ b2,
    const unsigned short* __restrict__ PW, const unsigned short* __restrict__ PW1,
    unsigned short* __restrict__ Hb, float* __restrict__ px,
    unsigned* __restrict__ bar, float* __restrict__ out)
{
  __shared__ alignas(16) unsigned short hfull[16 * 512];    // 16 KB, swizzled
  __shared__ alignas(16) char w1lds[65536];                 // 64 KB W1 frags
  __shared__ alignas(16) unsigned short hstage[16][136];    // 4.25 KB
  __shared__ alignas(16) float xg[16][4];                   // [v0,v1,x0,x1]

  const int tid = threadIdx.x;
  const int l  = tid & 63, w = tid >> 6;
  const int lm = l & 15,  ld = l >> 4;
  const int rt = blockIdx.x & 63, sl = blockIdx.x >> 6;
  const int row0 = rt * 16;
  char* hfullB = reinterpret_cast<char*>(hfull);

  unsigned* fl1 = bar + rt * 4;           // [sl] h published (value = step+1)
  unsigned* fl2 = bar + 1024 + rt * 4;    // [sl] px published (value = step)

  // ---- persistent gate-weight fragments (96/wave, loaded once) ----
  short8 BW[2][3][16];
  {
    const short8* pws = reinterpret_cast<const short8*>(PW);
#pragma unroll
    for (int ct = 0; ct < 2; ++ct)
#pragma unroll
      for (int g = 0; g < 3; ++g)
#pragma unroll
        for (int kk = 0; kk < 16; ++kk)
          BW[ct][g][kk] = pws[(size_t)((((sl * 4 + w) * 6 + g * 2 + ct) * 16 + kk) * 64 + l)];
  }
  // ---- W1 slice -> LDS (wave w copies hidden block sl*4+w, 16 KB) ----
  {
    const short8* pw1s = reinterpret_cast<const short8*>(PW1);
#pragma unroll
    for (int kk = 0; kk < 16; ++kk) {
      short8 v = pw1s[(size_t)(((sl * 4 + w) * 16 + kk) * 64 + l)];
      *reinterpret_cast<short8*>(w1lds + (size_t)((w * 16 + kk) * 1024 + l * 16)) = v;
    }
  }

  // ---- per-lane constants ----
  f32x4 wvx[2][3]; float bi[2][3], bh[2][3];
#pragma unroll
  for (int ct = 0; ct < 2; ++ct)
#pragma unroll
    for (int g = 0; g < 3; ++g) {
      int jg = g * 512 + sl * 128 + w * 32 + ct * 16 + lm;
      wvx[ct][g] = *reinterpret_cast<const f32x4*>(Wih + (size_t)jg * 4);
      bi[ct][g] = bih[jg];
      bh[ct][g] = bhh[jg];
    }
  const int ic = (sl * 4 + w) * 16 + lm;
  const float b1v = b1[ic];
  const float w2a = W2[ic], w2b = W2[256 + ic];
  const float b2c = b2[l & 1];

  float xcur = 0.f, vcur = 0.f;
  if (tid < 32) {
    int row = tid >> 1, c = tid & 1;
    xcur = X0[(row0 + row) * 2 + c];
    vcur = V[(size_t)(row0 + row) * 1024 + c];   // v_0
    xg[row][c] = vcur;
    xg[row][2 + c] = xcur;
  }
  float hp[2][4];
#pragma unroll
  for (int q = 0; q < 2; ++q)
#pragma unroll
    for (int r = 0; r < 4; ++r) hp[q][r] = 0.f;
  __syncthreads();

  const int rbA = lm * 1024, swA = (lm & 7) << 4;   // A rows = the 16 rowtile rows

  for (int i = 0; i <= Ssz; ++i) {
    f32x4 acc[2][3];
#pragma unroll
    for (int q = 0; q < 2; ++q)
#pragma unroll
      for (int g = 0; g < 3; ++g) acc[q][g] = (f32x4){0.f, 0.f, 0.f, 0.f};

    if (i > 0) {
      // ---- poll S1(i): all 4 producer WGs published h_{i-1} ----
      pollflags(fl1 + (l & 3), (unsigned)i);

      // ---- FILL: 16 rows x 512 cols -> swizzled LDS (4 gload16/thread) ----
      {
        const char* hsrc = reinterpret_cast<const char*>(
            Hb + (size_t)((i - 1) & 1) * (1024 * 512) + (size_t)row0 * 512);
        uint4v fb[4];
#pragma unroll
        for (int j = 0; j < 4; ++j)
          fb[j] = gload16(hsrc + (size_t)(tid + 256 * j) * 16);
        vwait0();
#pragma unroll
        for (int j = 0; j < 4; ++j) {
          const int c = tid + 256 * j;
          const int row = c >> 6, c16 = c & 63;
          *reinterpret_cast<uint4v*>(hfullB + row * 1024 + ((c16 * 16) ^ ((row & 7) << 4))) = fb[j];
        }
      }
      __syncthreads();   // B0: FILL complete (cross-wave rows)

      // ---- MLP (hidden block sl*4+w, 16 cols): px -> publish ----
      {
        f32x4 am = (f32x4){0.f, 0.f, 0.f, 0.f};
#pragma unroll
        for (int kk = 0; kk < 16; ++kk) {
          short8 a = *reinterpret_cast<const short8*>(hfullB + rbA + ((ld * 16 + kk * 64) ^ swA));
          short8 b = *reinterpret_cast<const short8*>(w1lds + (w * 16 + kk) * 1024 + l * 16);
          am = __builtin_amdgcn_mfma_f32_16x16x32_bf16(a, b, am, 0, 0, 0);
        }
        float pa[4], pb[4];
#pragma unroll
        for (int r = 0; r < 4; ++r) {
          float mv = fmaxf(am[r] + b1v, 0.f);
          pa[r] = mv * w2a;
          pb[r] = mv * w2b;
        }
#pragma unroll
        for (int off = 1; off < 16; off <<= 1)
#pragma unroll
          for (int r = 0; r < 4; ++r) {
            pa[r] += __shfl_xor(pa[r], off);
            pb[r] += __shfl_xor(pb[r], off);
          }
        if (lm == 0) {
          const int slot = sl * 4 + w;
#pragma unroll
          for (int r = 0; r < 4; ++r) {
            int row = ld * 4 + r;
            gstore4(px + ((size_t)(rt * 16 + row) * 2 + 0) * 16 + slot,
                    __builtin_bit_cast(unsigned, pa[r]));
            gstore4(px + ((size_t)(rt * 16 + row) * 2 + 1) * 16 + slot,
                    __builtin_bit_cast(unsigned, pb[r]));
          }
        }
      }
      asm volatile("s_waitcnt vmcnt(0)" ::: "memory");   // own px at MALL
      __syncthreads();   // B1: all waves' px drained
      if (tid == 0) gstore4(fl2 + sl, (unsigned)i);      // arrive S2(i)

      // ---- gh GEMM for step i (overlaps peers' MLP + S2 skew) ----
      if (i < Ssz) {
#pragma unroll
        for (int kk = 0; kk < 16; ++kk) {
          short8 a = *reinterpret_cast<const short8*>(hfullB + rbA + ((ld * 16 + kk * 64) ^ swA));
          acc[0][0] = __builtin_amdgcn_mfma_f32_16x16x32_bf16(a, BW[0][0][kk], acc[0][0], 0, 0, 0);
          acc[1][0] = __builtin_amdgcn_mfma_f32_16x16x32_bf16(a, BW[1][0][kk], acc[1][0], 0, 0, 0);
          acc[0][1] = __builtin_amdgcn_mfma_f32_16x16x32_bf16(a, BW[0][1][kk], acc[0][1], 0, 0, 0);
          acc[1][1] = __builtin_amdgcn_mfma_f32_16x16x32_bf16(a, BW[1][1][kk], acc[1][1], 0, 0, 0);
          acc[0][2] = __builtin_amdgcn_mfma_f32_16x16x32_bf16(a, BW[0][2][kk], acc[0][2], 0, 0, 0);
          acc[1][2] = __builtin_amdgcn_mfma_f32_16x16x32_bf16(a, BW[1][2][kk], acc[1][2], 0, 0, 0);
        }
      }

      // ---- poll S2(i): wave 0 only (feeds x update) ----
      if (w == 0) pollflags(fl2 + (l & 3), (unsigned)i);

      // ---- x update (tid<32): x_{i-1} = x_{i-2} + v_{i-1} + res ----
      if (tid < 32) {
        int row = tid >> 1, c = tid & 1;
        const float* pc = px + ((size_t)(rt * 16 + row) * 2 + c) * 16;
        f32x4 s0 = __builtin_bit_cast(f32x4, gload16(pc + 0));
        f32x4 s1 = __builtin_bit_cast(f32x4, gload16(pc + 4));
        f32x4 s2 = __builtin_bit_cast(f32x4, gload16(pc + 8));
        f32x4 s3 = __builtin_bit_cast(f32x4, gload16(pc + 12));
        vwait0();
        float s = b2c;
#pragma unroll
        for (int r = 0; r < 4; ++r) s += s0[r] + s1[r] + s2[r] + s3[r];
        float xt = xcur + vcur + s;
        xcur = xt;
        if ((row >> 2) == sl)    // distributed out write: slice sl owns rows sl*4..+4
          out[(size_t)(row0 + row) * 1024 + (i - 1) * 2 + c] = xt;
        vcur = (i < Ssz) ? V[(size_t)(row0 + row) * 1024 + i * 2 + c] : 0.f;
        xg[row][c] = vcur;
        xg[row][2 + c] = xt;
      }
      __syncthreads();   // B2: xg ready; GEMM reads of hfull done
    }

    if (i < Ssz) {
      // ---- gate math -> h_i + hstage ----
#pragma unroll
      for (int ct = 0; ct < 2; ++ct) {
#pragma unroll
        for (int r = 0; r < 4; ++r) {
          const int m = ld * 4 + r;
          const f32x4 xv = *reinterpret_cast<const f32x4*>(&xg[m][0]);
          float gv0 = wvx[ct][0][0]*xv[0] + wvx[ct][0][1]*xv[1] + wvx[ct][0][2]*xv[2] + wvx[ct][0][3]*xv[3];
          float gv1 = wvx[ct][1][0]*xv[0] + wvx[ct][1][1]*xv[1] + wvx[ct][1][2]*xv[2] + wvx[ct][1][3]*xv[3];
          float gv2 = wvx[ct][2][0]*xv[0] + wvx[ct][2][1]*xv[1] + wvx[ct][2][2]*xv[2] + wvx[ct][2][3]*xv[3];
          float rr = sigm(gv0 + bi[ct][0] + bh[ct][0] + acc[ct][0][r]);
          float zz = sigm(gv1 + bi[ct][1] + bh[ct][1] + acc[ct][1][r]);
          float nn = tanh_f(gv2 + bi[ct][2] + rr * (acc[ct][2][r] + bh[ct][2]));
          float ht = (1.f - zz) * nn + zz * hp[ct][r];
          hp[ct][r] = ht;
          hstage[m][w * 32 + ct * 16 + lm] = f2bf(ht);
        }
      }
      __syncthreads();   // B3: hstage complete

      // ---- publish h_i (16 rows x 128 cols) + arrive S1(i+1) ----
      {
        int row = tid >> 4, seg = tid & 15;
        uint4v hv = *reinterpret_cast<const uint4v*>(&hstage[row][seg * 8]);
        gstore16(Hb + (size_t)(i & 1) * (1024 * 512)
                    + (size_t)(row0 + row) * 512 + sl * 128 + seg * 8, hv);
      }
      asm volatile("s_waitcnt vmcnt(0)" ::: "memory");
      __syncthreads();
      if (tid == 0) gstore4(fl1 + sl, (unsigned)(i + 1));
    }
  }
}

extern "C" void kernel_launch(void* const* d_in, const int* in_sizes, int n_in,
                              void* d_out, int out_size, void* d_ws, size_t ws_size,
                              hipStream_t stream) {
  const float* X0  = (const float*)d_in[0];
  const float* V   = (const float*)d_in[1];
  const float* Wih = (const float*)d_in[2];
  const float* Whh = (const float*)d_in[3];
  const float* bih = (const float*)d_in[4];
  const float* bhh = (const float*)d_in[5];
  const float* W1  = (const float*)d_in[6];
  const float* b1  = (const float*)d_in[7];
  const float* W2  = (const float*)d_in[8];
  const float* b2  = (const float*)d_in[9];
  float* out = (float*)d_out;

  char* ws = (char*)d_ws;
  unsigned short* PW  = (unsigned short*)(ws + WS_PW);
  unsigned short* PW1 = (unsigned short*)(ws + WS_PW1);
  unsigned short* Hb  = (unsigned short*)(ws + WS_HB);
  float*          px  = (float*)(ws + WS_PX);
  unsigned*       bar = (unsigned*)(ws + WS_BAR);

  pack_whh_k<<<384, 256, 0, stream>>>(Whh, PW, bar);
  pack_w1_k<<<64, 256, 0, stream>>>(W1, PW1);
  gru_main<<<256, 256, 0, stream>>>(X0, V, Wih, bih, bhh, b1, W2, b2,
                                    PW, PW1, Hb, px, bar, out);
}

// Round 14
// 3335.380 us; speedup vs baseline: 1.8459x; 1.3897x over previous
//
#include <hip/hip_runtime.h>

#define Ssz 512

typedef __attribute__((ext_vector_type(8))) short short8;
typedef __attribute__((ext_vector_type(4))) float f32x4;
typedef __attribute__((ext_vector_type(4))) unsigned uint4v;
typedef __attribute__((ext_vector_type(2))) unsigned uint2v;

// ---- ws layout (bytes) ----
#define WS_PW   0u            // 1.5 MB packed gate weights
#define WS_PW1  1572864u      // 256 KB packed W1
#define WS_HB   1835008u      // 2 MB Hbuf[2][1024][512] bf16
#define WS_PX   3932160u      // 256 KB px[rt32][row32][c2][slot16]{f32 val,u32 epoch}
#define WS_BAR  4456448u      // 1 KB fl1[rt32][sl8]

__device__ __forceinline__ unsigned short f2bf(float f) {
  unsigned int u = __builtin_bit_cast(unsigned int, f);
  u += 0x7fffu + ((u >> 16) & 1u);   // RNE (finite inputs)
  return (unsigned short)(u >> 16);
}
__device__ __forceinline__ float sigm(float x) {
  x = fminf(fmaxf(x, -30.f), 30.f);
  return 1.f / (1.f + __expf(-x));
}
__device__ __forceinline__ float tanh_f(float x) {
  x = fminf(fmaxf(x, -15.f), 15.f);
  float e = __expf(2.f * x);
  return (e - 1.f) / (e + 1.f);
}

// ---- cache-bypassing (device-coherent) ops: data at MALL (verified R5/R9) ----
__device__ __forceinline__ uint4v gload16(const void* p) {
  uint4v d;
  asm volatile("global_load_dwordx4 %0, %1, off sc0 sc1" : "=v"(d) : "v"(p));
  return d;
}
__device__ __forceinline__ uint2v gload8(const void* p) {
  uint2v d;
  asm volatile("global_load_dwordx2 %0, %1, off sc0 sc1" : "=v"(d) : "v"(p));
  return d;
}
__device__ __forceinline__ unsigned gload4(const void* p) {
  unsigned d;
  asm volatile("global_load_dword %0, %1, off sc0 sc1" : "=v"(d) : "v"(p));
  return d;
}
__device__ __forceinline__ void gstore16(void* p, uint4v v) {
  asm volatile("global_store_dwordx4 %0, %1, off sc0 sc1" :: "v"(p), "v"(v) : "memory");
}
__device__ __forceinline__ void gstore8(void* p, uint2v v) {
  asm volatile("global_store_dwordx2 %0, %1, off sc0 sc1" :: "v"(p), "v"(v) : "memory");
}
__device__ __forceinline__ void gstore4(void* p, unsigned v) {
  asm volatile("global_store_dword %0, %1, off sc0 sc1" :: "v"(p), "v"(v) : "memory");
}
__device__ __forceinline__ void vwait0() {
  asm volatile("s_waitcnt vmcnt(0)" ::: "memory");
  __builtin_amdgcn_sched_barrier(0);
}
// All-lane poll (R9-verified): lane polls one flag, wave proceeds on __all.
__device__ __forceinline__ void pollflags(const unsigned* fp, unsigned target) {
  for (;;) {
    unsigned v = gload4(fp);
    vwait0();
    if (__all((int)(v >= target))) break;
    __builtin_amdgcn_s_sleep(1);
  }
}

// Pack W_hh [1536,512] f32 -> fragment-ordered bf16 (layout = R9: pure 16-col
// block mapping; the 64-col slicing indexes it as slO = sl*2+(w>>1), ch = w&1).
// byte offset (((slO*6+g*2+ch)*16+kk)*64+l)*16 holds
// W_hh[g*512 + slO*32 + ch*16 + (l&15)][kk*32 + (l>>4)*8 + e].
// Blocks 0..31 zero the px epoch region (256 KB) + block 0 zeroes fl1 flags
// every launch (replay determinism after the one-time 0xAA ws poison).
__global__ void pack_whh_k(const float* __restrict__ Wp, unsigned short* __restrict__ dst,
                           unsigned* __restrict__ pxz, unsigned* __restrict__ barz) {
  if (blockIdx.x < 32) {
    unsigned* base = pxz + blockIdx.x * 2048;
    for (int i = threadIdx.x; i < 2048; i += 256) base[i] = 0u;
  }
  if (blockIdx.x == 0) {
    for (int i = threadIdx.x; i < 256; i += 256) barz[i] = 0u;
  }
  int T = blockIdx.x * 256 + threadIdx.x;
  int l  = T & 63;
  int r1 = T >> 6;
  int kk = r1 & 15;
  int r2 = r1 >> 4;
  int q  = r2 % 6;
  int slO = r2 / 6;
  int g = q >> 1, ch = q & 1;
  int j  = g * 512 + slO * 32 + ch * 16 + (l & 15);
  int kb = kk * 32 + (l >> 4) * 8;
  const float* src = Wp + j * 512 + kb;
  short8 o;
#pragma unroll
  for (int e = 0; e < 8; ++e) o[e] = (short)f2bf(src[e]);
  *reinterpret_cast<short8*>(dst + (size_t)T * 8) = o;
}

// Pack W1 [256,512] f32 -> fragment-ordered bf16 (unchanged).
// [hb16][kk16][l64]x16B: holds W1[hb*16+(l&15)][kk*32+(l>>4)*8+e]
__global__ void pack_w1_k(const float* __restrict__ W1, unsigned short* __restrict__ dst) {
  int T = blockIdx.x * 256 + threadIdx.x;
  int l  = T & 63;
  int r1 = T >> 6;
  int kk = r1 & 15;
  int hb = r1 >> 4;
  int j  = hb * 16 + (l & 15);
  int kb = kk * 32 + (l >> 4) * 8;
  const float* src = W1 + j * 512 + kb;
  short8 o;
#pragma unroll
  for (int e = 0; e < 8; ++e) o[e] = (short)f2bf(src[e]);
  *reinterpret_cast<short8*>(dst + (size_t)T * 8) = o;
}

// 256 WGs x 256 threads: 32 rowtiles (32 rows) x 8 slices (64 gate cols).
// R9 protocol with: (a) FILL halved (32KB/WG/step, 8MB aggregate) + S1
// fan-in 8; (b) px carries {val, epoch} 8B pairs -> no px drain, no S2
// flag, x-updater's poll IS the data read; (c) per-wave frag budget kept
// at R9's 48+16 (no spill; frags live in AGPRs). LDS padded >80KB -> 1 WG/CU.
// Wave w: gate cols w*16 of the WG's 64; MLP rows (w&1)*16, hidden block
// hb = sl*2+(w>>1) (= px slot). x update: wave 0, lane l -> row l>>1, c=l&1.
__global__ __launch_bounds__(256, 1) void gru_main(
    const float* __restrict__ X0, const float* __restrict__ V,
    const float* __restrict__ Wih, const float* __restrict__ bih,
    const float* __restrict__ bhh, const float* __restrict__ b1,
    const float* __restrict__ W2, const float* __restrict__ b2,
    const unsigned short* __restrict__ PW, const unsigned short* __restrict__ PW1,
    unsigned short* __restrict__ Hb, unsigned* __restrict__ px,
    unsigned* __restrict__ bar, float* __restrict__ out)
{
  __shared__ alignas(16) unsigned short hfull[32 * 512];   // 32 KB, swizzled
  __shared__ alignas(16) unsigned short hstage[32][72];    // 4.5 KB (144B stride)
  __shared__ alignas(16) float xg[32][4];                  // [v0,v1,x0,x1]
  __shared__ char lds_pad[45056];                          // force 1 WG/CU

  const int tid = threadIdx.x;
  const int l  = tid & 63, w = tid >> 6;
  const int lm = l & 15,  ld = l >> 4;
  const int rt = blockIdx.x & 31, sl = blockIdx.x >> 5;
  const int row0 = rt * 32;
  char* hfullB = reinterpret_cast<char*>(hfull);
  if (out == nullptr) lds_pad[tid] = 1;   // keep pad live (never executes)

  unsigned* fl1 = bar + rt * 8;           // [sl] h published (value = step+1)
  unsigned* pxrt = px + (size_t)rt * 2048;  // [row32][c2][slot16][2 words]

  // ---- persistent weight fragments (48 + 16 per wave, loaded once) ----
  const int slO = sl * 2 + (w >> 1), chw = w & 1;
  short8 BW[3][16];
  {
    const short8* pws = reinterpret_cast<const short8*>(PW);
#pragma unroll
    for (int g = 0; g < 3; ++g)
#pragma unroll
      for (int kk = 0; kk < 16; ++kk)
        BW[g][kk] = pws[(size_t)((((slO * 6 + g * 2 + chw) * 16 + kk) * 64 + l))];
  }
  const int hb = sl * 2 + (w >> 1);       // MLP hidden block = px slot
  short8 BM[16];
  {
    const short8* pw1s = reinterpret_cast<const short8*>(PW1);
#pragma unroll
    for (int kk = 0; kk < 16; ++kk)
      BM[kk] = pw1s[(size_t)((hb * 16 + kk) * 64 + l)];
  }

  // ---- per-lane constants ----
  const int jcol = sl * 64 + w * 16 + lm;   // gate column
  f32x4 wvx[3]; float bi[3], bh[3];
#pragma unroll
  for (int g = 0; g < 3; ++g) {
    int jg = g * 512 + jcol;
    wvx[g] = *reinterpret_cast<const f32x4*>(Wih + (size_t)jg * 4);
    bi[g] = bih[jg];
    bh[g] = bhh[jg];
  }
  const int ic = hb * 16 + lm;
  const float b1v = b1[ic];
  const float w2a = W2[ic], w2b = W2[256 + ic];
  const float b2c = b2[l & 1];

  // ---- x state (wave 0: lane l -> row l>>1, c = l&1) ----
  float xcur = 0.f, vcur = 0.f;
  if (w == 0) {
    int row = l >> 1, c = l & 1;
    xcur = X0[(row0 + row) * 2 + c];
    vcur = V[(size_t)(row0 + row) * 1024 + c];   // v_0
    xg[row][c] = vcur;
    xg[row][2 + c] = xcur;
  }
  float hp[2][4];
#pragma unroll
  for (int q = 0; q < 2; ++q)
#pragma unroll
    for (int r = 0; r < 4; ++r) hp[q][r] = 0.f;
  __syncthreads();

  const int rbA0 = lm * 1024;               // GEMM A rows 0-15
  const int rbA1 = (16 + lm) * 1024;        // GEMM A rows 16-31 ((16+lm)&7==lm&7)
  const int rbB  = ((w & 1) * 16 + lm) * 1024;  // MLP A rows (w&1)*16..+16
  const int swz  = (lm & 7) << 4;

  for (int i = 0; i <= Ssz; ++i) {
    f32x4 acc[2][3];
#pragma unroll
    for (int q = 0; q < 2; ++q)
#pragma unroll
      for (int g = 0; g < 3; ++g) acc[q][g] = (f32x4){0.f, 0.f, 0.f, 0.f};

    if (i > 0) {
      // ---- poll S1(i): all 8 producer WGs published h_{i-1} ----
      pollflags(fl1 + (l & 7), (unsigned)i);

      // ---- FILL: 32 rows x 512 cols -> swizzled LDS (8 gload16/thread) ----
      {
        const char* hsrc = reinterpret_cast<const char*>(
            Hb + (size_t)((i - 1) & 1) * (1024 * 512) + (size_t)row0 * 512);
        uint4v fb[8];
#pragma unroll
        for (int j = 0; j < 8; ++j)
          fb[j] = gload16(hsrc + (size_t)(tid + 256 * j) * 16);
        vwait0();
#pragma unroll
        for (int j = 0; j < 8; ++j) {
          const int c = tid + 256 * j;
          const int row = c >> 6, c16 = c & 63;
          *reinterpret_cast<uint4v*>(hfullB + row * 1024 + ((c16 * 16) ^ ((row & 7) << 4))) = fb[j];
        }
      }
      // (wave's own MLP rows may span other waves' FILL rows -> barrier below
      //  covers GEMM; MLP uses rows (w&1)*16 which thread-block FILL spread
      //  across all waves -> need the barrier BEFORE MLP too)
      __syncthreads();   // B0: FILL complete

      // ---- MLP rows (w&1)*16..+16, hidden block hb: px {val,epoch} publish ----
      {
        f32x4 am = (f32x4){0.f, 0.f, 0.f, 0.f};
#pragma unroll
        for (int kk = 0; kk < 16; ++kk) {
          short8 a = *reinterpret_cast<const short8*>(hfullB + rbB + ((ld * 16 + kk * 64) ^ swz));
          am = __builtin_amdgcn_mfma_f32_16x16x32_bf16(a, BM[kk], am, 0, 0, 0);
        }
        float pa[4], pb[4];
#pragma unroll
        for (int r = 0; r < 4; ++r) {
          float mv = fmaxf(am[r] + b1v, 0.f);
          pa[r] = mv * w2a;
          pb[r] = mv * w2b;
        }
#pragma unroll
        for (int off = 1; off < 16; off <<= 1)
#pragma unroll
          for (int r = 0; r < 4; ++r) {
            pa[r] += __shfl_xor(pa[r], off);
            pb[r] += __shfl_xor(pb[r], off);
          }
        if (lm == 0) {
#pragma unroll
          for (int r = 0; r < 4; ++r) {
            int row = (w & 1) * 16 + ld * 4 + r;
            uint2v v0, v1;
            v0[0] = __builtin_bit_cast(unsigned, pa[r]); v0[1] = (unsigned)i;
            v1[0] = __builtin_bit_cast(unsigned, pb[r]); v1[1] = (unsigned)i;
            gstore8(pxrt + (size_t)(((row * 2 + 0) * 16 + hb) * 2), v0);
            gstore8(pxrt + (size_t)(((row * 2 + 1) * 16 + hb) * 2), v1);
          }
        }
        // no drain, no flag: epoch rides with the data
      }

      // ---- gh GEMM for step i ----
      if (i < Ssz) {
#pragma unroll
        for (int kk = 0; kk < 16; ++kk) {
          const int o = (ld * 16 + kk * 64) ^ swz;
          short8 a0 = *reinterpret_cast<const short8*>(hfullB + rbA0 + o);
          short8 a1 = *reinterpret_cast<const short8*>(hfullB + rbA1 + o);
          acc[0][0] = __builtin_amdgcn_mfma_f32_16x16x32_bf16(a0, BW[0][kk], acc[0][0], 0, 0, 0);
          acc[1][0] = __builtin_amdgcn_mfma_f32_16x16x32_bf16(a1, BW[0][kk], acc[1][0], 0, 0, 0);
          acc[0][1] = __builtin_amdgcn_mfma_f32_16x16x32_bf16(a0, BW[1][kk], acc[0][1], 0, 0, 0);
          acc[1][1] = __builtin_amdgcn_mfma_f32_16x16x32_bf16(a1, BW[1][kk], acc[1][1], 0, 0, 0);
          acc[0][2] = __builtin_amdgcn_mfma_f32_16x16x32_bf16(a0, BW[2][kk], acc[0][2], 0, 0, 0);
          acc[1][2] = __builtin_amdgcn_mfma_f32_16x16x32_bf16(a1, BW[2][kk], acc[1][2], 0, 0, 0);
        }
      }

      // ---- x update (wave 0): poll-read embedded px; x_{i-1}; stage xg ----
      if (w == 0) {
        const int row = l >> 1, c = l & 1;
        const unsigned* pc = pxrt + (size_t)((row * 2 + c) * 16) * 2;
        uint2v ps[16];
        for (;;) {
#pragma unroll
          for (int s = 0; s < 16; ++s) ps[s] = gload8(pc + s * 2);
          vwait0();
          bool ok = true;
#pragma unroll
          for (int s = 0; s < 16; ++s) ok &= (ps[s][1] == (unsigned)i);
          if (__all((int)ok)) break;
          __builtin_amdgcn_s_sleep(1);
        }
        float s = b2c;
#pragma unroll
        for (int r = 0; r < 16; ++r) s += __builtin_bit_cast(float, ps[r][0]);
        float xt = xcur + vcur + s;
        xcur = xt;
        if ((row >> 2) == sl)    // distributed out: slice sl owns rows sl*4..+4
          out[(size_t)(row0 + row) * 1024 + (i - 1) * 2 + c] = xt;
        vcur = (i < Ssz) ? V[(size_t)(row0 + row) * 1024 + i * 2 + c] : 0.f;
        xg[row][c] = vcur;
        xg[row][2 + c] = xt;
      }
      __syncthreads();   // B1: xg ready; GEMM reads of hfull done
    }

    if (i < Ssz) {
      // ---- gate math -> h_i + hstage (wave w: cols w*16, rows 0..31) ----
#pragma unroll
      for (int rt2 = 0; rt2 < 2; ++rt2) {
#pragma unroll
        for (int r = 0; r < 4; ++r) {
          const int m = rt2 * 16 + ld * 4 + r;
          const f32x4 xv = *reinterpret_cast<const f32x4*>(&xg[m][0]);
          float gv0 = wvx[0][0]*xv[0] + wvx[0][1]*xv[1] + wvx[0][2]*xv[2] + wvx[0][3]*xv[3];
          float gv1 = wvx[1][0]*xv[0] + wvx[1][1]*xv[1] + wvx[1][2]*xv[2] + wvx[1][3]*xv[3];
          float gv2 = wvx[2][0]*xv[0] + wvx[2][1]*xv[1] + wvx[2][2]*xv[2] + wvx[2][3]*xv[3];
          float rr = sigm(gv0 + bi[0] + bh[0] + acc[rt2][0][r]);
          float zz = sigm(gv1 + bi[1] + bh[1] + acc[rt2][1][r]);
          float nn = tanh_f(gv2 + bi[2] + rr * (acc[rt2][2][r] + bh[2]));
          float ht = (1.f - zz) * nn + zz * hp[rt2][r];
          hp[rt2][r] = ht;
          hstage[m][w * 16 + lm] = f2bf(ht);
        }
      }
      __syncthreads();   // B2: hstage complete

      // ---- publish h_i (32 rows x 64 cols) + arrive S1(i+1) ----
      {
        int row = tid >> 3, seg = tid & 7;
        uint4v hv = *reinterpret_cast<const uint4v*>(&hstage[row][seg * 8]);
        gstore16(Hb + (size_t)(i & 1) * (1024 * 512)
                    + (size_t)(row0 + row) * 512 + sl * 64 + seg * 8, hv);
      }
      asm volatile("s_waitcnt vmcnt(0)" ::: "memory");
      __syncthreads();
      if (tid == 0) gstore4(fl1 + sl, (unsigned)(i + 1));
    }
  }
}

extern "C" void kernel_launch(void* const* d_in, const int* in_sizes, int n_in,
                              void* d_out, int out_size, void* d_ws, size_t ws_size,
                              hipStream_t stream) {
  const float* X0  = (const float*)d_in[0];
  const float* V   = (const float*)d_in[1];
  const float* Wih = (const float*)d_in[2];
  const float* Whh = (const float*)d_in[3];
  const float* bih = (const float*)d_in[4];
  const float* bhh = (const float*)d_in[5];
  const float* W1  = (const float*)d_in[6];
  const float* b1  = (const float*)d_in[7];
  const float* W2  = (const float*)d_in[8];
  const float* b2  = (const float*)d_in[9];
  float* out = (float*)d_out;

  char* ws = (char*)d_ws;
  unsigned short* PW  = (unsigned short*)(ws + WS_PW);
  unsigned short* PW1 = (unsigned short*)(ws + WS_PW1);
  unsigned short* Hb  = (unsigned short*)(ws + WS_HB);
  unsigned*       px  = (unsigned*)(ws + WS_PX);
  unsigned*       bar = (unsigned*)(ws + WS_BAR);

  pack_whh_k<<<384, 256, 0, stream>>>(Whh, PW, px, bar);
  pack_w1_k<<<64, 256, 0, stream>>>(W1, PW1);
  gru_main<<<256, 256, 0, stream>>>(X0, V, Wih, bih, bhh, b1, W2, b2,
                                    PW, PW1, Hb, px, bar, out);
}